// Round 1
// baseline (380.208 us; speedup 1.0000x reference)
//
#include <hip/hip_runtime.h>
#include <stdint.h>

#define B_N  4096
#define P_N  19000
#define D_N  4000
#define T_N  32
#define H1_N 2048
#define H2_N 1024

typedef __bf16 bf16x8 __attribute__((ext_vector_type(8)));
typedef float  f32x4  __attribute__((ext_vector_type(4)));

__device__ __forceinline__ unsigned short f2bf(float f) {
  union { float f; uint32_t u; } v; v.f = f;
  uint32_t u = v.u;
  uint32_t r = (u + 0x7fffu + ((u >> 16) & 1u)) >> 16;  // RNE
  return (unsigned short)r;
}

__device__ __forceinline__ void gload16(const void* g, void* l) {
  __builtin_amdgcn_global_load_lds((const __attribute__((address_space(1))) void*)g,
                                   (__attribute__((address_space(3))) void*)l,
                                   16, 0, 0);
}

// K1: per-drug sums of W1 rows (deduped targets). S_A from block-0 rows, S_B from block-1 rows.
__global__ __launch_bounds__(256) void k_dsum(const int* __restrict__ dt, const float* __restrict__ W1,
                                              float* __restrict__ SA, float* __restrict__ SB) {
  __shared__ int tgt[T_N];
  __shared__ int ok[T_N];
  const int d   = blockIdx.x;
  const int tid = threadIdx.x;
  if (tid < T_N) tgt[tid] = dt[d * T_N + tid];
  __syncthreads();
  if (tid < T_N) {
    int v = 1, t = tgt[tid];
    for (int j = 0; j < tid; ++j) v &= (tgt[j] != t);  // multi-hot: count each unique target once
    ok[tid] = v;
  }
  __syncthreads();
  const int c0 = tid * 8;
  float aA[8] = {0,0,0,0,0,0,0,0};
  float aB[8] = {0,0,0,0,0,0,0,0};
  for (int t = 0; t < T_N; ++t) {
    if (ok[t]) {  // uniform branch (shared)
      const int row = tgt[t];
      const float4* pa = (const float4*)(W1 + (size_t)row * H1_N + c0);
      const float4* pb = (const float4*)(W1 + (size_t)(P_N + 1 + row) * H1_N + c0);
      float4 x0 = pa[0], x1 = pa[1], y0 = pb[0], y1 = pb[1];
      aA[0]+=x0.x; aA[1]+=x0.y; aA[2]+=x0.z; aA[3]+=x0.w;
      aA[4]+=x1.x; aA[5]+=x1.y; aA[6]+=x1.z; aA[7]+=x1.w;
      aB[0]+=y0.x; aB[1]+=y0.y; aB[2]+=y0.z; aB[3]+=y0.w;
      aB[4]+=y1.x; aB[5]+=y1.y; aB[6]+=y1.z; aB[7]+=y1.w;
    }
  }
  float4 o;
  o.x=aA[0]; o.y=aA[1]; o.z=aA[2]; o.w=aA[3];
  *(float4*)(SA + (size_t)d * H1_N + c0)     = o;
  o.x=aA[4]; o.y=aA[5]; o.z=aA[6]; o.w=aA[7];
  *(float4*)(SA + (size_t)d * H1_N + c0 + 4) = o;
  o.x=aB[0]; o.y=aB[1]; o.z=aB[2]; o.w=aB[3];
  *(float4*)(SB + (size_t)d * H1_N + c0)     = o;
  o.x=aB[4]; o.y=aB[5]; o.z=aB[6]; o.w=aB[7];
  *(float4*)(SB + (size_t)d * H1_N + c0 + 4) = o;
}

// W2 [K=2048][N=1024] f32 -> W2T [N][K] bf16 (so GEMM B-operand is K-contiguous)
__global__ __launch_bounds__(256) void k_w2t(const float* __restrict__ W2, unsigned short* __restrict__ W2T) {
  __shared__ float tile[32][33];
  const int bx = blockIdx.x & 31;   // n-tile (1024/32)
  const int by = blockIdx.x >> 5;   // k-tile (2048/32)
  const int tx = threadIdx.x & 31, ty = threadIdx.x >> 5;
  #pragma unroll
  for (int i = 0; i < 4; ++i)
    tile[ty + i*8][tx] = W2[(size_t)(by*32 + ty + i*8) * H2_N + bx*32 + tx];
  __syncthreads();
  #pragma unroll
  for (int i = 0; i < 4; ++i) {
    const int n = bx*32 + ty + i*8;
    const int k = by*32 + tx;
    W2T[(size_t)n * H1_N + k] = f2bf(tile[tx][ty + i*8]);
  }
}

// K2: h1[r,:] = relu(S_A[dA] + S_B[dB] + cA*W1[P] + cB*W1[2P+1] + b1), bf16 out.
// Rows [0,B): order_1 (dA=drug0). Rows [B,2B): order_2 (dA=drug1).
__global__ __launch_bounds__(256) void k_h1(const int* __restrict__ dp, const float* __restrict__ conc,
                                            const float* __restrict__ W1, const float* __restrict__ b1,
                                            const float* __restrict__ SA, const float* __restrict__ SB,
                                            unsigned short* __restrict__ h1) {
  const int rI   = blockIdx.x;
  const int swap = (rI >= B_N) ? 1 : 0;
  const int rr   = swap ? rI - B_N : rI;
  const int dA = dp[2*rr + swap];
  const int dB = dp[2*rr + (1 - swap)];
  const float cA = conc[2*rr + swap];
  const float cB = conc[2*rr + (1 - swap)];
  const int c0 = threadIdx.x * 8;
  const float4* sa = (const float4*)(SA + (size_t)dA * H1_N + c0);
  const float4* sb = (const float4*)(SB + (size_t)dB * H1_N + c0);
  const float4* wp = (const float4*)(W1 + (size_t)P_N * H1_N + c0);
  const float4* wq = (const float4*)(W1 + (size_t)(2*P_N + 1) * H1_N + c0);
  const float4* bp = (const float4*)(b1 + c0);
  unsigned short res[8];
  #pragma unroll
  for (int v = 0; v < 2; ++v) {
    float4 a = sa[v], b = sb[v], p = wp[v], q = wq[v], z = bp[v];
    res[v*4+0] = f2bf(fmaxf(a.x + b.x + cA*p.x + cB*q.x + z.x, 0.f));
    res[v*4+1] = f2bf(fmaxf(a.y + b.y + cA*p.y + cB*q.y + z.y, 0.f));
    res[v*4+2] = f2bf(fmaxf(a.z + b.z + cA*p.z + cB*q.z + z.z, 0.f));
    res[v*4+3] = f2bf(fmaxf(a.w + b.w + cA*p.w + cB*q.w + z.w, 0.f));
  }
  *(uint4*)(h1 + (size_t)rI * H1_N + c0) = *(uint4*)res;
}

// K3: h2[8192,1024] = relu(h1 @ W2 + b2), bf16 MFMA 16x16x32, 128x128 tile, BK=64.
// LDS layout [row][slot] with slot ^= (row&7) XOR-swizzle applied on BOTH the
// global-source side (pre-swizzled lane addresses feeding linear global_load_lds)
// and the ds_read side (rule 21: both-sides-or-neither).
__global__ __launch_bounds__(256) void k_gemm(const unsigned short* __restrict__ A,
                                              const unsigned short* __restrict__ Bm,
                                              const float* __restrict__ b2,
                                              float* __restrict__ C) {
  __shared__ unsigned short As[128 * 64];
  __shared__ unsigned short Bs[128 * 64];
  const int tid  = threadIdx.x;
  const int wv   = tid >> 6;
  const int lane = tid & 63;
  const int m0 = (blockIdx.x >> 3) * 128;
  const int n0 = (blockIdx.x & 7) * 128;
  const int wm = (wv >> 1) * 64;
  const int wn = (wv & 1) * 64;
  const int r = lane & 15;
  const int g = lane >> 4;
  const int srow = lane >> 3;                 // row within 8-row chunk
  const int slot = (lane & 7) ^ srow;         // logical 16B slot this lane must fetch

  f32x4 acc[4][4] = {};

  for (int kt = 0; kt < H1_N / 64; ++kt) {
    const int k0 = kt * 64;
    #pragma unroll
    for (int i = 0; i < 4; ++i) {
      const int c   = i * 4 + wv;             // 1KB chunk id (wave-uniform)
      const int row = c * 8 + srow;
      gload16(A  + (size_t)(m0 + row) * H1_N + k0 + slot * 8, (char*)As + c * 1024);
      gload16(Bm + (size_t)(n0 + row) * H1_N + k0 + slot * 8, (char*)Bs + c * 1024);
    }
    __syncthreads();                           // drains vmcnt before compute
    #pragma unroll
    for (int kk = 0; kk < 2; ++kk) {
      bf16x8 af[4], bfr[4];
      #pragma unroll
      for (int mi = 0; mi < 4; ++mi) {
        const int row = wm + mi * 16 + r;
        const int s   = (kk * 4 + g) ^ (row & 7);
        af[mi] = *(const bf16x8*)((const char*)As + row * 128 + s * 16);
      }
      #pragma unroll
      for (int ni = 0; ni < 4; ++ni) {
        const int col = wn + ni * 16 + r;
        const int s   = (kk * 4 + g) ^ (col & 7);
        bfr[ni] = *(const bf16x8*)((const char*)Bs + col * 128 + s * 16);
      }
      #pragma unroll
      for (int mi = 0; mi < 4; ++mi)
        #pragma unroll
        for (int ni = 0; ni < 4; ++ni)
          acc[mi][ni] = __builtin_amdgcn_mfma_f32_16x16x32_bf16(af[mi], bfr[ni], acc[mi][ni], 0, 0, 0);
    }
    __syncthreads();                           // protect LDS before next stage
  }
  // C/D layout (m89-verified): col = lane&15, row = (lane>>4)*4 + q
  #pragma unroll
  for (int ni = 0; ni < 4; ++ni) {
    const int col = n0 + wn + ni * 16 + r;
    const float bb = b2[col];
    #pragma unroll
    for (int mi = 0; mi < 4; ++mi)
      #pragma unroll
      for (int q = 0; q < 4; ++q) {
        const int rowg = m0 + wm + mi * 16 + g * 4 + q;
        C[(size_t)rowg * H2_N + col] = fmaxf(acc[mi][ni][q] + bb, 0.f);
      }
  }
}

// K4: out[row] = h2[row,:] . W3 + b3   (one wave per row)
__global__ __launch_bounds__(256) void k_out(const float* __restrict__ h2, const float* __restrict__ W3,
                                             const float* __restrict__ b3, float* __restrict__ out) {
  const int row  = blockIdx.x * 4 + (threadIdx.x >> 6);
  const int lane = threadIdx.x & 63;
  const float4* hp = (const float4*)(h2 + (size_t)row * H2_N);
  const float4* wp = (const float4*)W3;
  float s = 0.f;
  #pragma unroll
  for (int j = 0; j < 4; ++j) {
    float4 h = hp[j * 64 + lane];
    float4 w = wp[j * 64 + lane];
    s += h.x * w.x + h.y * w.y + h.z * w.z + h.w * w.w;
  }
  #pragma unroll
  for (int o = 32; o > 0; o >>= 1) s += __shfl_down(s, o, 64);
  if (lane == 0) out[row] = s + b3[0];
}

extern "C" void kernel_launch(void* const* d_in, const int* in_sizes, int n_in,
                              void* d_out, int out_size, void* d_ws, size_t ws_size,
                              hipStream_t stream) {
  const int*   dp   = (const int*)d_in[0];
  const int*   dt   = (const int*)d_in[1];
  const float* conc = (const float*)d_in[2];
  const float* W1   = (const float*)d_in[3];
  const float* b1   = (const float*)d_in[4];
  const float* W2   = (const float*)d_in[5];
  const float* b2   = (const float*)d_in[6];
  const float* W3   = (const float*)d_in[7];
  const float* b3   = (const float*)d_in[8];
  float* out = (float*)d_out;

  // ws layout (bytes):
  //   [0,            32768000)   S_A  f32 [4000][2048]
  //   [32768000,     65536000)   S_B  f32 [4000][2048]
  //   [65536000,     99090432)   h1   bf16 [8192][2048]
  //   [99090432,    103284736)   W2T  bf16 [1024][2048]
  //   h2 f32 [8192][1024] aliases S_A/S_B region (dead after k_h1). Total ~103.3 MB.
  char* ws = (char*)d_ws;
  float*          SA  = (float*)ws;
  float*          SB  = (float*)(ws + 32768000);
  unsigned short* h1  = (unsigned short*)(ws + 65536000);
  unsigned short* w2t = (unsigned short*)(ws + 99090432);
  float*          h2  = (float*)ws;

  k_dsum<<<D_N,    256, 0, stream>>>(dt, W1, SA, SB);
  k_w2t <<<2048,   256, 0, stream>>>(W2, w2t);
  k_h1  <<<2*B_N,  256, 0, stream>>>(dp, conc, W1, b1, SA, SB, h1);
  k_gemm<<<512,    256, 0, stream>>>(h1, w2t, b2, h2);
  k_out <<<2048,   256, 0, stream>>>(h2, W3, b3, out);
}

// Round 2
// 306.025 us; speedup vs baseline: 1.2424x; 1.2424x over previous
//
#include <hip/hip_runtime.h>
#include <stdint.h>

#define B_N  4096
#define P_N  19000
#define D_N  4000
#define T_N  32
#define H1_N 2048
#define H2_N 1024

typedef __bf16 bf16x8 __attribute__((ext_vector_type(8)));
typedef float  f32x4  __attribute__((ext_vector_type(4)));

__device__ __forceinline__ unsigned short f2bf(float f) {
  union { float f; uint32_t u; } v; v.f = f;
  uint32_t u = v.u;
  uint32_t r = (u + 0x7fffu + ((u >> 16) & 1u)) >> 16;  // RNE
  return (unsigned short)r;
}

__device__ __forceinline__ float bflo(uint32_t u) {  // low bf16 of a packed u32
  union { uint32_t u; float f; } v; v.u = u << 16; return v.f;
}
__device__ __forceinline__ float bfhi(uint32_t u) {  // high bf16
  union { uint32_t u; float f; } v; v.u = u & 0xffff0000u; return v.f;
}

__device__ __forceinline__ void gload16(const void* g, void* l) {
  __builtin_amdgcn_global_load_lds((const __attribute__((address_space(1))) void*)g,
                                   (__attribute__((address_space(3))) void*)l,
                                   16, 0, 0);
}

// K0: W1 [38002][2048] f32 -> bf16. One block per row; thread covers 8 cols.
__global__ __launch_bounds__(256) void k_conv(const float* __restrict__ W1,
                                              unsigned short* __restrict__ W1b) {
  const size_t base = (size_t)blockIdx.x * H1_N + threadIdx.x * 8;
  const float4* p = (const float4*)(W1 + base);
  float4 x = p[0], y = p[1];
  unsigned short r[8] = { f2bf(x.x), f2bf(x.y), f2bf(x.z), f2bf(x.w),
                          f2bf(y.x), f2bf(y.y), f2bf(y.z), f2bf(y.w) };
  *(uint4*)(W1b + base) = *(uint4*)r;
}

// K1: per-drug sums of bf16 W1 rows. Branch-free: fixed 32-trip loop, dup rows
// get weight 0 (multi-hot semantics: each unique target counted once).
__global__ __launch_bounds__(256) void k_dsum(const int* __restrict__ dt,
                                              const unsigned short* __restrict__ W1b,
                                              float* __restrict__ SA, float* __restrict__ SB) {
  __shared__ int   tgt[T_N];
  __shared__ float wgt[T_N];
  const int d   = blockIdx.x;
  const int tid = threadIdx.x;
  if (tid < T_N) tgt[tid] = dt[d * T_N + tid];
  __syncthreads();
  if (tid < T_N) {
    int v = 1, t = tgt[tid];
    for (int j = 0; j < tid; ++j) v &= (tgt[j] != t);
    wgt[tid] = (float)v;
  }
  __syncthreads();
  const int c0 = tid * 8;
  float aA[8] = {0,0,0,0,0,0,0,0};
  float aB[8] = {0,0,0,0,0,0,0,0};
  #pragma unroll 4
  for (int t = 0; t < T_N; ++t) {
    const float  w   = wgt[t];
    const size_t row = (size_t)tgt[t];
    uint4 a = *(const uint4*)(W1b + row * H1_N + c0);
    uint4 b = *(const uint4*)(W1b + (19001 + row) * H1_N + c0);
    uint32_t au[4] = {a.x, a.y, a.z, a.w};
    uint32_t bu[4] = {b.x, b.y, b.z, b.w};
    #pragma unroll
    for (int k = 0; k < 4; ++k) {
      aA[2*k]   = fmaf(w, bflo(au[k]), aA[2*k]);
      aA[2*k+1] = fmaf(w, bfhi(au[k]), aA[2*k+1]);
      aB[2*k]   = fmaf(w, bflo(bu[k]), aB[2*k]);
      aB[2*k+1] = fmaf(w, bfhi(bu[k]), aB[2*k+1]);
    }
  }
  float4 o;
  o.x=aA[0]; o.y=aA[1]; o.z=aA[2]; o.w=aA[3];
  *(float4*)(SA + (size_t)d * H1_N + c0)     = o;
  o.x=aA[4]; o.y=aA[5]; o.z=aA[6]; o.w=aA[7];
  *(float4*)(SA + (size_t)d * H1_N + c0 + 4) = o;
  o.x=aB[0]; o.y=aB[1]; o.z=aB[2]; o.w=aB[3];
  *(float4*)(SB + (size_t)d * H1_N + c0)     = o;
  o.x=aB[4]; o.y=aB[5]; o.z=aB[6]; o.w=aB[7];
  *(float4*)(SB + (size_t)d * H1_N + c0 + 4) = o;
}

// W2 [K=2048][N=1024] f32 -> W2T [N][K] bf16 (so GEMM B-operand is K-contiguous)
__global__ __launch_bounds__(256) void k_w2t(const float* __restrict__ W2, unsigned short* __restrict__ W2T) {
  __shared__ float tile[32][33];
  const int bx = blockIdx.x & 31;   // n-tile (1024/32)
  const int by = blockIdx.x >> 5;   // k-tile (2048/32)
  const int tx = threadIdx.x & 31, ty = threadIdx.x >> 5;
  #pragma unroll
  for (int i = 0; i < 4; ++i)
    tile[ty + i*8][tx] = W2[(size_t)(by*32 + ty + i*8) * H2_N + bx*32 + tx];
  __syncthreads();
  #pragma unroll
  for (int i = 0; i < 4; ++i) {
    const int n = bx*32 + ty + i*8;
    const int k = by*32 + tx;
    W2T[(size_t)n * H1_N + k] = f2bf(tile[tx][ty + i*8]);
  }
}

// K2: h1[r,:] = relu(S_A[dA] + S_B[dB] + cA*W1[P] + cB*W1[2P+1] + b1), bf16 out.
// Rows [0,B): order_1 (dA=drug0). Rows [B,2B): order_2 (dA=drug1).
__global__ __launch_bounds__(256) void k_h1(const int* __restrict__ dp, const float* __restrict__ conc,
                                            const float* __restrict__ W1, const float* __restrict__ b1,
                                            const float* __restrict__ SA, const float* __restrict__ SB,
                                            unsigned short* __restrict__ h1) {
  const int rI   = blockIdx.x;
  const int swap = (rI >= B_N) ? 1 : 0;
  const int rr   = swap ? rI - B_N : rI;
  const int dA = dp[2*rr + swap];
  const int dB = dp[2*rr + (1 - swap)];
  const float cA = conc[2*rr + swap];
  const float cB = conc[2*rr + (1 - swap)];
  const int c0 = threadIdx.x * 8;
  const float4* sa = (const float4*)(SA + (size_t)dA * H1_N + c0);
  const float4* sb = (const float4*)(SB + (size_t)dB * H1_N + c0);
  const float4* wp = (const float4*)(W1 + (size_t)P_N * H1_N + c0);
  const float4* wq = (const float4*)(W1 + (size_t)(2*P_N + 1) * H1_N + c0);
  const float4* bp = (const float4*)(b1 + c0);
  unsigned short res[8];
  #pragma unroll
  for (int v = 0; v < 2; ++v) {
    float4 a = sa[v], b = sb[v], p = wp[v], q = wq[v], z = bp[v];
    res[v*4+0] = f2bf(fmaxf(a.x + b.x + cA*p.x + cB*q.x + z.x, 0.f));
    res[v*4+1] = f2bf(fmaxf(a.y + b.y + cA*p.y + cB*q.y + z.y, 0.f));
    res[v*4+2] = f2bf(fmaxf(a.z + b.z + cA*p.z + cB*q.z + z.z, 0.f));
    res[v*4+3] = f2bf(fmaxf(a.w + b.w + cA*p.w + cB*q.w + z.w, 0.f));
  }
  *(uint4*)(h1 + (size_t)rI * H1_N + c0) = *(uint4*)res;
}

// K3: h2[8192,1024] = relu(h1 @ W2 + b2), bf16 MFMA 16x16x32, 128x128 tile, BK=64.
// LDS layout [row][slot] with slot ^= (row&7) XOR-swizzle applied on BOTH the
// global-source side (pre-swizzled lane addresses feeding linear global_load_lds)
// and the ds_read side (rule 21: both-sides-or-neither).
__global__ __launch_bounds__(256) void k_gemm(const unsigned short* __restrict__ A,
                                              const unsigned short* __restrict__ Bm,
                                              const float* __restrict__ b2,
                                              float* __restrict__ C) {
  __shared__ unsigned short As[128 * 64];
  __shared__ unsigned short Bs[128 * 64];
  const int tid  = threadIdx.x;
  const int wv   = tid >> 6;
  const int lane = tid & 63;
  const int m0 = (blockIdx.x >> 3) * 128;
  const int n0 = (blockIdx.x & 7) * 128;
  const int wm = (wv >> 1) * 64;
  const int wn = (wv & 1) * 64;
  const int r = lane & 15;
  const int g = lane >> 4;
  const int srow = lane >> 3;                 // row within 8-row chunk
  const int slot = (lane & 7) ^ srow;         // logical 16B slot this lane must fetch

  f32x4 acc[4][4] = {};

  for (int kt = 0; kt < H1_N / 64; ++kt) {
    const int k0 = kt * 64;
    #pragma unroll
    for (int i = 0; i < 4; ++i) {
      const int c   = i * 4 + wv;             // 1KB chunk id (wave-uniform)
      const int row = c * 8 + srow;
      gload16(A  + (size_t)(m0 + row) * H1_N + k0 + slot * 8, (char*)As + c * 1024);
      gload16(Bm + (size_t)(n0 + row) * H1_N + k0 + slot * 8, (char*)Bs + c * 1024);
    }
    __syncthreads();                           // drains vmcnt before compute
    #pragma unroll
    for (int kk = 0; kk < 2; ++kk) {
      bf16x8 af[4], bfr[4];
      #pragma unroll
      for (int mi = 0; mi < 4; ++mi) {
        const int row = wm + mi * 16 + r;
        const int s   = (kk * 4 + g) ^ (row & 7);
        af[mi] = *(const bf16x8*)((const char*)As + row * 128 + s * 16);
      }
      #pragma unroll
      for (int ni = 0; ni < 4; ++ni) {
        const int col = wn + ni * 16 + r;
        const int s   = (kk * 4 + g) ^ (col & 7);
        bfr[ni] = *(const bf16x8*)((const char*)Bs + col * 128 + s * 16);
      }
      #pragma unroll
      for (int mi = 0; mi < 4; ++mi)
        #pragma unroll
        for (int ni = 0; ni < 4; ++ni)
          acc[mi][ni] = __builtin_amdgcn_mfma_f32_16x16x32_bf16(af[mi], bfr[ni], acc[mi][ni], 0, 0, 0);
    }
    __syncthreads();                           // protect LDS before next stage
  }
  // C/D layout (m89-verified): col = lane&15, row = (lane>>4)*4 + q
  #pragma unroll
  for (int ni = 0; ni < 4; ++ni) {
    const int col = n0 + wn + ni * 16 + r;
    const float bb = b2[col];
    #pragma unroll
    for (int mi = 0; mi < 4; ++mi)
      #pragma unroll
      for (int q = 0; q < 4; ++q) {
        const int rowg = m0 + wm + mi * 16 + g * 4 + q;
        C[(size_t)rowg * H2_N + col] = fmaxf(acc[mi][ni][q] + bb, 0.f);
      }
  }
}

// K4: out[row] = h2[row,:] . W3 + b3   (one wave per row)
__global__ __launch_bounds__(256) void k_out(const float* __restrict__ h2, const float* __restrict__ W3,
                                             const float* __restrict__ b3, float* __restrict__ out) {
  const int row  = blockIdx.x * 4 + (threadIdx.x >> 6);
  const int lane = threadIdx.x & 63;
  const float4* hp = (const float4*)(h2 + (size_t)row * H2_N);
  const float4* wp = (const float4*)W3;
  float s = 0.f;
  #pragma unroll
  for (int j = 0; j < 4; ++j) {
    float4 h = hp[j * 64 + lane];
    float4 w = wp[j * 64 + lane];
    s += h.x * w.x + h.y * w.y + h.z * w.z + h.w * w.w;
  }
  #pragma unroll
  for (int o = 32; o > 0; o >>= 1) s += __shfl_down(s, o, 64);
  if (lane == 0) out[row] = s + b3[0];
}

extern "C" void kernel_launch(void* const* d_in, const int* in_sizes, int n_in,
                              void* d_out, int out_size, void* d_ws, size_t ws_size,
                              hipStream_t stream) {
  const int*   dp   = (const int*)d_in[0];
  const int*   dt   = (const int*)d_in[1];
  const float* conc = (const float*)d_in[2];
  const float* W1   = (const float*)d_in[3];
  const float* b1   = (const float*)d_in[4];
  const float* W2   = (const float*)d_in[5];
  const float* b2   = (const float*)d_in[6];
  const float* W3   = (const float*)d_in[7];
  const float* b3   = (const float*)d_in[8];
  float* out = (float*)d_out;

  // ws layout (bytes):
  //   region0 [0, 155656192): W1b bf16 [38002][2048]   (dead after k_dsum)
  //     after k_dsum, region0 is reused:
  //       h1  bf16 [8192][2048]  at      0 .. 33554432
  //       w2t bf16 [1024][2048]  at 33554432 .. 37748736
  //       h2  f32  [8192][1024]  at 37748736 .. 71303168
  //   SA f32 [4000][2048] at 155656192
  //   SB f32 [4000][2048] at 188424192 .. 221192192   (total ~221.2 MB)
  char* ws = (char*)d_ws;
  unsigned short* W1b = (unsigned short*)ws;
  unsigned short* h1  = (unsigned short*)ws;
  unsigned short* w2t = (unsigned short*)(ws + 33554432);
  float*          h2  = (float*)(ws + 37748736);
  float*          SA  = (float*)(ws + 155656192);
  float*          SB  = (float*)(ws + 188424192);

  k_conv<<<38002,  256, 0, stream>>>(W1, W1b);
  k_dsum<<<D_N,    256, 0, stream>>>(dt, W1b, SA, SB);
  k_w2t <<<2048,   256, 0, stream>>>(W2, w2t);   // w2t aliases W1b region: must run after k_dsum
  k_h1  <<<2*B_N,  256, 0, stream>>>(dp, conc, W1, b1, SA, SB, h1);
  k_gemm<<<512,    256, 0, stream>>>(h1, w2t, b2, h2);
  k_out <<<2048,   256, 0, stream>>>(h2, W3, b3, out);
}

// Round 4
// 274.799 us; speedup vs baseline: 1.3836x; 1.1136x over previous
//
#include <hip/hip_runtime.h>
#include <stdint.h>

#define B_N  4096
#define P_N  19000
#define D_N  4000
#define T_N  32
#define H1_N 2048
#define H2_N 1024

typedef __bf16 bf16x8 __attribute__((ext_vector_type(8)));
typedef float  f32x4  __attribute__((ext_vector_type(4)));

__device__ __forceinline__ unsigned short f2bf(float f) {
  union { float f; uint32_t u; } v; v.f = f;
  uint32_t u = v.u;
  uint32_t r = (u + 0x7fffu + ((u >> 16) & 1u)) >> 16;  // RNE
  return (unsigned short)r;
}

__device__ __forceinline__ float bflo(uint32_t u) {  // low bf16 of a packed u32
  union { uint32_t u; float f; } v; v.u = u << 16; return v.f;
}
__device__ __forceinline__ float bfhi(uint32_t u) {  // high bf16
  union { uint32_t u; float f; } v; v.u = u & 0xffff0000u; return v.f;
}

__device__ __forceinline__ void gload16(const void* g, void* l) {
  __builtin_amdgcn_global_load_lds((const __attribute__((address_space(1))) void*)g,
                                   (__attribute__((address_space(3))) void*)l,
                                   16, 0, 0);
}

// K-1: mark drugs actually referenced by drug_pairs (single block: zero + scatter, no races)
__global__ __launch_bounds__(256) void k_setflags(const int* __restrict__ dp,
                                                  unsigned char* __restrict__ flags) {
  const int tid = threadIdx.x;
  for (int i = tid; i < D_N; i += 256) flags[i] = 0;
  __syncthreads();
  for (int i = tid; i < 2 * B_N; i += 256) flags[dp[i]] = 1;
}

// K0: W1 [38002][2048] f32 -> bf16. One block per row; thread covers 8 cols.
__global__ __launch_bounds__(256) void k_conv(const float* __restrict__ W1,
                                              unsigned short* __restrict__ W1b) {
  const size_t base = (size_t)blockIdx.x * H1_N + threadIdx.x * 8;
  const float4* p = (const float4*)(W1 + base);
  float4 x = p[0], y = p[1];
  unsigned short r[8] = { f2bf(x.x), f2bf(x.y), f2bf(x.z), f2bf(x.w),
                          f2bf(y.x), f2bf(y.y), f2bf(y.z), f2bf(y.w) };
  *(uint4*)(W1b + base) = *(uint4*)r;
}

// K1: per-drug sums of bf16 W1 rows (dup targets weighted 0; unused drugs skipped).
// Accumulate f32, store bf16.
__global__ __launch_bounds__(256) void k_dsum(const int* __restrict__ dt,
                                              const unsigned char* __restrict__ flags,
                                              const unsigned short* __restrict__ W1b,
                                              unsigned short* __restrict__ SAb,
                                              unsigned short* __restrict__ SBb) {
  const int d = blockIdx.x;
  if (!flags[d]) return;                      // block-uniform early exit
  __shared__ int   tgt[T_N];
  __shared__ float wgt[T_N];
  const int tid = threadIdx.x;
  if (tid < T_N) tgt[tid] = dt[d * T_N + tid];
  __syncthreads();
  if (tid < T_N) {
    int v = 1, t = tgt[tid];
    for (int j = 0; j < tid; ++j) v &= (tgt[j] != t);
    wgt[tid] = (float)v;
  }
  __syncthreads();
  const int c0 = tid * 8;
  float aA[8] = {0,0,0,0,0,0,0,0};
  float aB[8] = {0,0,0,0,0,0,0,0};
  #pragma unroll 4
  for (int t = 0; t < T_N; ++t) {
    const float  w   = wgt[t];
    const size_t row = (size_t)tgt[t];
    uint4 a = *(const uint4*)(W1b + row * H1_N + c0);
    uint4 b = *(const uint4*)(W1b + (19001 + row) * H1_N + c0);
    uint32_t au[4] = {a.x, a.y, a.z, a.w};
    uint32_t bu[4] = {b.x, b.y, b.z, b.w};
    #pragma unroll
    for (int k = 0; k < 4; ++k) {
      aA[2*k]   = fmaf(w, bflo(au[k]), aA[2*k]);
      aA[2*k+1] = fmaf(w, bfhi(au[k]), aA[2*k+1]);
      aB[2*k]   = fmaf(w, bflo(bu[k]), aB[2*k]);
      aB[2*k+1] = fmaf(w, bfhi(bu[k]), aB[2*k+1]);
    }
  }
  unsigned short oa[8], ob[8];
  #pragma unroll
  for (int k = 0; k < 8; ++k) { oa[k] = f2bf(aA[k]); ob[k] = f2bf(aB[k]); }
  *(uint4*)(SAb + (size_t)d * H1_N + c0) = *(uint4*)oa;
  *(uint4*)(SBb + (size_t)d * H1_N + c0) = *(uint4*)ob;
}

// W2 [K=2048][N=1024] f32 -> W2T [N][K] bf16 (so GEMM B-operand is K-contiguous)
__global__ __launch_bounds__(256) void k_w2t(const float* __restrict__ W2, unsigned short* __restrict__ W2T) {
  __shared__ float tile[32][33];
  const int bx = blockIdx.x & 31;   // n-tile (1024/32)
  const int by = blockIdx.x >> 5;   // k-tile (2048/32)
  const int tx = threadIdx.x & 31, ty = threadIdx.x >> 5;
  #pragma unroll
  for (int i = 0; i < 4; ++i)
    tile[ty + i*8][tx] = W2[(size_t)(by*32 + ty + i*8) * H2_N + bx*32 + tx];
  __syncthreads();
  #pragma unroll
  for (int i = 0; i < 4; ++i) {
    const int n = bx*32 + ty + i*8;
    const int k = by*32 + tx;
    W2T[(size_t)n * H1_N + k] = f2bf(tile[tx][ty + i*8]);
  }
}

// K2: h1[r,:] = relu(S_A[dA] + S_B[dB] + cA*W1[P] + cB*W1[2P+1] + b1), bf16 out.
// Rows [0,B): order_1 (dA=drug0). Rows [B,2B): order_2 (dA=drug1).
__global__ __launch_bounds__(256) void k_h1(const int* __restrict__ dp, const float* __restrict__ conc,
                                            const float* __restrict__ W1, const float* __restrict__ b1,
                                            const unsigned short* __restrict__ SAb,
                                            const unsigned short* __restrict__ SBb,
                                            unsigned short* __restrict__ h1) {
  const int rI   = blockIdx.x;
  const int swap = (rI >= B_N) ? 1 : 0;
  const int rr   = swap ? rI - B_N : rI;
  const int dA = dp[2*rr + swap];
  const int dB = dp[2*rr + (1 - swap)];
  const float cA = conc[2*rr + swap];
  const float cB = conc[2*rr + (1 - swap)];
  const int c0 = threadIdx.x * 8;
  uint4 ua = *(const uint4*)(SAb + (size_t)dA * H1_N + c0);
  uint4 ub = *(const uint4*)(SBb + (size_t)dB * H1_N + c0);
  uint32_t au[4] = {ua.x, ua.y, ua.z, ua.w};
  uint32_t bu[4] = {ub.x, ub.y, ub.z, ub.w};
  const float4* wp = (const float4*)(W1 + (size_t)P_N * H1_N + c0);
  const float4* wq = (const float4*)(W1 + (size_t)(2*P_N + 1) * H1_N + c0);
  const float4* bp = (const float4*)(b1 + c0);
  float a[8], b[8], p[8], q[8], z[8];
  #pragma unroll
  for (int k = 0; k < 4; ++k) {
    a[2*k] = bflo(au[k]); a[2*k+1] = bfhi(au[k]);
    b[2*k] = bflo(bu[k]); b[2*k+1] = bfhi(bu[k]);
  }
  float4 p0 = wp[0], p1 = wp[1], q0 = wq[0], q1 = wq[1], z0 = bp[0], z1 = bp[1];
  p[0]=p0.x;p[1]=p0.y;p[2]=p0.z;p[3]=p0.w;p[4]=p1.x;p[5]=p1.y;p[6]=p1.z;p[7]=p1.w;
  q[0]=q0.x;q[1]=q0.y;q[2]=q0.z;q[3]=q0.w;q[4]=q1.x;q[5]=q1.y;q[6]=q1.z;q[7]=q1.w;
  z[0]=z0.x;z[1]=z0.y;z[2]=z0.z;z[3]=z0.w;z[4]=z1.x;z[5]=z1.y;z[6]=z1.z;z[7]=z1.w;
  unsigned short res[8];
  #pragma unroll
  for (int k = 0; k < 8; ++k)
    res[k] = f2bf(fmaxf(a[k] + b[k] + cA*p[k] + cB*q[k] + z[k], 0.f));
  *(uint4*)(h1 + (size_t)rI * H1_N + c0) = *(uint4*)res;
}

// K3: fused h2 = relu(h1 @ W2 + b2) and partial[nblk][row] = sum_col relu(h2)*W3[col].
// bf16 MFMA 16x16x32, 128x128 tile, BK=64, both-sides XOR slot swizzle (rule 21).
__global__ __launch_bounds__(256) void k_gemm(const unsigned short* __restrict__ A,
                                              const unsigned short* __restrict__ Bm,
                                              const float* __restrict__ b2,
                                              const float* __restrict__ W3,
                                              float* __restrict__ partial) {
  __shared__ unsigned short As[128 * 64];
  __shared__ unsigned short Bs[128 * 64];
  __shared__ float ps[128];
  const int tid  = threadIdx.x;
  const int wv   = tid >> 6;
  const int lane = tid & 63;
  const int m0 = (blockIdx.x >> 3) * 128;
  const int n0 = (blockIdx.x & 7) * 128;
  const int wm = (wv >> 1) * 64;
  const int wn = (wv & 1) * 64;
  const int r = lane & 15;
  const int g = lane >> 4;
  const int srow = lane >> 3;                 // row within 8-row chunk
  const int slot = (lane & 7) ^ srow;         // logical 16B slot this lane must fetch

  f32x4 acc[4][4] = {};

  for (int kt = 0; kt < H1_N / 64; ++kt) {
    const int k0 = kt * 64;
    #pragma unroll
    for (int i = 0; i < 4; ++i) {
      const int c   = i * 4 + wv;             // 1KB chunk id (wave-uniform)
      const int row = c * 8 + srow;
      gload16(A  + (size_t)(m0 + row) * H1_N + k0 + slot * 8, (char*)As + c * 1024);
      gload16(Bm + (size_t)(n0 + row) * H1_N + k0 + slot * 8, (char*)Bs + c * 1024);
    }
    __syncthreads();                           // drains vmcnt before compute
    #pragma unroll
    for (int kk = 0; kk < 2; ++kk) {
      bf16x8 af[4], bfr[4];
      #pragma unroll
      for (int mi = 0; mi < 4; ++mi) {
        const int row = wm + mi * 16 + r;
        const int s   = (kk * 4 + g) ^ (row & 7);
        af[mi] = *(const bf16x8*)((const char*)As + row * 128 + s * 16);
      }
      #pragma unroll
      for (int ni = 0; ni < 4; ++ni) {
        const int col = wn + ni * 16 + r;
        const int s   = (kk * 4 + g) ^ (col & 7);
        bfr[ni] = *(const bf16x8*)((const char*)Bs + col * 128 + s * 16);
      }
      #pragma unroll
      for (int mi = 0; mi < 4; ++mi)
        #pragma unroll
        for (int ni = 0; ni < 4; ++ni)
          acc[mi][ni] = __builtin_amdgcn_mfma_f32_16x16x32_bf16(af[mi], bfr[ni], acc[mi][ni], 0, 0, 0);
    }
    __syncthreads();                           // protect LDS before next stage
  }
  // Epilogue: C/D layout col=lane&15 (r), row=g*4+q within 16x16 fragment.
  // rowsum[mi][q] = sum_{ni} relu(acc+b2)*W3 over this lane's 4 cols, then
  // shfl-reduce over the 16-lane col group, combine the two wn waves via LDS.
  float b2v[4], w3v[4];
  #pragma unroll
  for (int ni = 0; ni < 4; ++ni) {
    const int col = n0 + wn + ni * 16 + r;
    b2v[ni] = b2[col];
    w3v[ni] = W3[col];
  }
  float rs[16];
  #pragma unroll
  for (int mi = 0; mi < 4; ++mi)
    #pragma unroll
    for (int q = 0; q < 4; ++q) {
      float s = 0.f;
      #pragma unroll
      for (int ni = 0; ni < 4; ++ni)
        s += fmaxf(acc[mi][ni][q] + b2v[ni], 0.f) * w3v[ni];
      rs[mi*4+q] = s;
    }
  #pragma unroll
  for (int o = 1; o < 16; o <<= 1)
    #pragma unroll
    for (int k = 0; k < 16; ++k)
      rs[k] += __shfl_xor(rs[k], o, 64);
  if ((wv & 1) == 0) {
    if (r == 0)
      #pragma unroll
      for (int mi = 0; mi < 4; ++mi)
        #pragma unroll
        for (int q = 0; q < 4; ++q)
          ps[wm + mi*16 + g*4 + q] = rs[mi*4+q];
  }
  __syncthreads();
  if ((wv & 1) == 1) {
    if (r == 0)
      #pragma unroll
      for (int mi = 0; mi < 4; ++mi)
        #pragma unroll
        for (int q = 0; q < 4; ++q) {
          const int rw = wm + mi*16 + g*4 + q;
          partial[(size_t)(blockIdx.x & 7) * (2*B_N) + m0 + rw] = ps[rw] + rs[mi*4+q];
        }
  }
}

// K4: out[i] = sum_j partial[j][i] + b3
__global__ __launch_bounds__(256) void k_fin(const float* __restrict__ partial,
                                             const float* __restrict__ b3,
                                             float* __restrict__ out) {
  const int i = blockIdx.x * 256 + threadIdx.x;
  float s = b3[0];
  #pragma unroll
  for (int j = 0; j < 8; ++j) s += partial[(size_t)j * (2*B_N) + i];
  out[i] = s;
}

extern "C" void kernel_launch(void* const* d_in, const int* in_sizes, int n_in,
                              void* d_out, int out_size, void* d_ws, size_t ws_size,
                              hipStream_t stream) {
  const int*   dp   = (const int*)d_in[0];
  const int*   dt   = (const int*)d_in[1];
  const float* conc = (const float*)d_in[2];
  const float* W1   = (const float*)d_in[3];
  const float* b1   = (const float*)d_in[4];
  const float* W2   = (const float*)d_in[5];
  const float* b2   = (const float*)d_in[6];
  const float* W3   = (const float*)d_in[7];
  const float* b3   = (const float*)d_in[8];
  float* out = (float*)d_out;

  // ws layout (bytes) — SAb/SBb are 4000*2048*2 = 16,384,000 B each (round-3
  // bug: SBb offset was 8000 B short, clobbering SAb rows 3998-3999):
  //   [0,         155656192)  W1b bf16 [38002][2048]  (dead after k_dsum)
  //      aliased after k_dsum by:
  //        h1       bf16 [8192][2048] at 0 .. 33554432
  //        partials f32  [8][8192]    at 33554432 .. 33816576
  //   [155656192, 172040192)  SAb bf16 [4000][2048]
  //   [172040192, 188424192)  SBb bf16 [4000][2048]
  //   [188424192, 192618496)  w2t bf16 [1024][2048]
  //   [192618496, 192622496)  flags u8 [4000]          (total ~192.6 MB)
  char* ws = (char*)d_ws;
  unsigned short* W1b   = (unsigned short*)ws;
  unsigned short* h1    = (unsigned short*)ws;
  float*          parts = (float*)(ws + 33554432);
  unsigned short* SAb   = (unsigned short*)(ws + 155656192);
  unsigned short* SBb   = (unsigned short*)(ws + 172040192);
  unsigned short* w2t   = (unsigned short*)(ws + 188424192);
  unsigned char*  flags = (unsigned char*)(ws + 192618496);

  k_setflags<<<1,     256, 0, stream>>>(dp, flags);
  k_conv    <<<38002, 256, 0, stream>>>(W1, W1b);
  k_w2t     <<<2048,  256, 0, stream>>>(W2, w2t);
  k_dsum    <<<D_N,   256, 0, stream>>>(dt, flags, W1b, SAb, SBb);
  k_h1      <<<2*B_N, 256, 0, stream>>>(dp, conc, W1, b1, SAb, SBb, h1);
  k_gemm    <<<512,   256, 0, stream>>>(h1, w2t, b2, W3, parts);
  k_fin     <<<32,    256, 0, stream>>>(parts, b3, out);
}

// Round 6
// 267.844 us; speedup vs baseline: 1.4195x; 1.0260x over previous
//
#include <hip/hip_runtime.h>
#include <stdint.h>

#define B_N  4096
#define P_N  19000
#define D_N  4000
#define T_N  32
#define H1_N 2048
#define H2_N 1024

typedef __bf16 bf16x8 __attribute__((ext_vector_type(8)));
typedef float  f32x4  __attribute__((ext_vector_type(4)));

__device__ __forceinline__ unsigned short f2bf(float f) {
  union { float f; uint32_t u; } v; v.f = f;
  uint32_t u = v.u;
  uint32_t r = (u + 0x7fffu + ((u >> 16) & 1u)) >> 16;  // RNE
  return (unsigned short)r;
}

__device__ __forceinline__ float bflo(uint32_t u) {  // low bf16 of a packed u32
  union { uint32_t u; float f; } v; v.u = u << 16; return v.f;
}
__device__ __forceinline__ float bfhi(uint32_t u) {  // high bf16
  union { uint32_t u; float f; } v; v.u = u & 0xffff0000u; return v.f;
}

__device__ __forceinline__ void gload16(const void* g, void* l) {
  __builtin_amdgcn_global_load_lds((const __attribute__((address_space(1))) void*)g,
                                   (__attribute__((address_space(3))) void*)l,
                                   16, 0, 0);
}

// K0 fused prep: blocks [0,38002) convert W1 f32->bf16; [38002,40050) transpose
// W2 -> bf16 [N][K]; block 40050 builds the used-drug flags.
__global__ __launch_bounds__(256) void k_prep(const float* __restrict__ W1,
                                              unsigned short* __restrict__ W1b,
                                              const float* __restrict__ W2,
                                              unsigned short* __restrict__ W2T,
                                              const int* __restrict__ dp,
                                              unsigned char* __restrict__ flags) {
  __shared__ float tile[32][33];
  const int b = blockIdx.x;
  if (b < 38002) {
    const size_t base = (size_t)b * H1_N + threadIdx.x * 8;
    const float4* p = (const float4*)(W1 + base);
    float4 x = p[0], y = p[1];
    unsigned short r[8] = { f2bf(x.x), f2bf(x.y), f2bf(x.z), f2bf(x.w),
                            f2bf(y.x), f2bf(y.y), f2bf(y.z), f2bf(y.w) };
    *(uint4*)(W1b + base) = *(uint4*)r;
  } else if (b < 38002 + 2048) {
    const int bb = b - 38002;
    const int bx = bb & 31;   // n-tile (1024/32)
    const int by = bb >> 5;   // k-tile (2048/32)
    const int tx = threadIdx.x & 31, ty = threadIdx.x >> 5;
    #pragma unroll
    for (int i = 0; i < 4; ++i)
      tile[ty + i*8][tx] = W2[(size_t)(by*32 + ty + i*8) * H2_N + bx*32 + tx];
    __syncthreads();
    #pragma unroll
    for (int i = 0; i < 4; ++i) {
      const int n = bx*32 + ty + i*8;
      const int k = by*32 + tx;
      W2T[(size_t)n * H1_N + k] = f2bf(tile[tx][ty + i*8]);
    }
  } else {
    const int tid = threadIdx.x;
    for (int i = tid; i < D_N; i += 256) flags[i] = 0;
    __syncthreads();
    for (int i = tid; i < 2 * B_N; i += 256) flags[dp[i]] = 1;
  }
}

// K1: per-drug sums of bf16 W1 rows (dup targets weighted 0; unused drugs skipped).
// Accumulate f32, store bf16.
__global__ __launch_bounds__(256) void k_dsum(const int* __restrict__ dt,
                                              const unsigned char* __restrict__ flags,
                                              const unsigned short* __restrict__ W1b,
                                              unsigned short* __restrict__ SAb,
                                              unsigned short* __restrict__ SBb) {
  const int d = blockIdx.x;
  if (!flags[d]) return;                      // block-uniform early exit
  __shared__ int   tgt[T_N];
  __shared__ float wgt[T_N];
  const int tid = threadIdx.x;
  if (tid < T_N) tgt[tid] = dt[d * T_N + tid];
  __syncthreads();
  if (tid < T_N) {
    int v = 1, t = tgt[tid];
    for (int j = 0; j < tid; ++j) v &= (tgt[j] != t);
    wgt[tid] = (float)v;
  }
  __syncthreads();
  const int c0 = tid * 8;
  float aA[8] = {0,0,0,0,0,0,0,0};
  float aB[8] = {0,0,0,0,0,0,0,0};
  #pragma unroll 4
  for (int t = 0; t < T_N; ++t) {
    const float  w   = wgt[t];
    const size_t row = (size_t)tgt[t];
    uint4 a = *(const uint4*)(W1b + row * H1_N + c0);
    uint4 b = *(const uint4*)(W1b + (19001 + row) * H1_N + c0);
    uint32_t au[4] = {a.x, a.y, a.z, a.w};
    uint32_t bu[4] = {b.x, b.y, b.z, b.w};
    #pragma unroll
    for (int k = 0; k < 4; ++k) {
      aA[2*k]   = fmaf(w, bflo(au[k]), aA[2*k]);
      aA[2*k+1] = fmaf(w, bfhi(au[k]), aA[2*k+1]);
      aB[2*k]   = fmaf(w, bflo(bu[k]), aB[2*k]);
      aB[2*k+1] = fmaf(w, bfhi(bu[k]), aB[2*k+1]);
    }
  }
  unsigned short oa[8], ob[8];
  #pragma unroll
  for (int k = 0; k < 8; ++k) { oa[k] = f2bf(aA[k]); ob[k] = f2bf(aB[k]); }
  *(uint4*)(SAb + (size_t)d * H1_N + c0) = *(uint4*)oa;
  *(uint4*)(SBb + (size_t)d * H1_N + c0) = *(uint4*)ob;
}

// K2: h1[r,:] = relu(S_A[dA] + S_B[dB] + cA*W1[P] + cB*W1[2P+1] + b1), bf16 out.
// Rows [0,B): order_1 (dA=drug0). Rows [B,2B): order_2 (dA=drug1).
__global__ __launch_bounds__(256) void k_h1(const int* __restrict__ dp, const float* __restrict__ conc,
                                            const float* __restrict__ W1, const float* __restrict__ b1,
                                            const unsigned short* __restrict__ SAb,
                                            const unsigned short* __restrict__ SBb,
                                            unsigned short* __restrict__ h1) {
  const int rI   = blockIdx.x;
  const int swap = (rI >= B_N) ? 1 : 0;
  const int rr   = swap ? rI - B_N : rI;
  const int dA = dp[2*rr + swap];
  const int dB = dp[2*rr + (1 - swap)];
  const float cA = conc[2*rr + swap];
  const float cB = conc[2*rr + (1 - swap)];
  const int c0 = threadIdx.x * 8;
  uint4 ua = *(const uint4*)(SAb + (size_t)dA * H1_N + c0);
  uint4 ub = *(const uint4*)(SBb + (size_t)dB * H1_N + c0);
  uint32_t au[4] = {ua.x, ua.y, ua.z, ua.w};
  uint32_t bu[4] = {ub.x, ub.y, ub.z, ub.w};
  const float4* wp = (const float4*)(W1 + (size_t)P_N * H1_N + c0);
  const float4* wq = (const float4*)(W1 + (size_t)(2*P_N + 1) * H1_N + c0);
  const float4* bp = (const float4*)(b1 + c0);
  float a[8], b[8], p[8], q[8], z[8];
  #pragma unroll
  for (int k = 0; k < 4; ++k) {
    a[2*k] = bflo(au[k]); a[2*k+1] = bfhi(au[k]);
    b[2*k] = bflo(bu[k]); b[2*k+1] = bfhi(bu[k]);
  }
  float4 p0 = wp[0], p1 = wp[1], q0 = wq[0], q1 = wq[1], z0 = bp[0], z1 = bp[1];
  p[0]=p0.x;p[1]=p0.y;p[2]=p0.z;p[3]=p0.w;p[4]=p1.x;p[5]=p1.y;p[6]=p1.z;p[7]=p1.w;
  q[0]=q0.x;q[1]=q0.y;q[2]=q0.z;q[3]=q0.w;q[4]=q1.x;q[5]=q1.y;q[6]=q1.z;q[7]=q1.w;
  z[0]=z0.x;z[1]=z0.y;z[2]=z0.z;z[3]=z0.w;z[4]=z1.x;z[5]=z1.y;z[6]=z1.z;z[7]=z1.w;
  unsigned short res[8];
  #pragma unroll
  for (int k = 0; k < 8; ++k)
    res[k] = f2bf(fmaxf(a[k] + b[k] + cA*p[k] + cB*q[k] + z[k], 0.f));
  *(uint4*)(h1 + (size_t)rI * H1_N + c0) = *(uint4*)res;
}

// K3: fused h2 = relu(h1 @ W2 + b2), out-partial = sum_col relu(h2)*W3[col].
// BM=64, BN=256, FULL K=2048 per block (ReLU forbids K-splitting — round-5 bug).
// Grid = 128 m-tiles x 4 nq = 512 blocks (2/CU). Each wave: 64x64 output
// (wn = wv*64), acc[4][4]. A re-read factor 4 (134 MB); 1 MB B-quarter-panels
// L2-pinned (XCD = bid%8, nq = bid&3). Both-sides XOR slot swizzle (rule 21).
__global__ __launch_bounds__(256, 2) void k_gemm(const unsigned short* __restrict__ A,
                                                 const unsigned short* __restrict__ Bm,
                                                 const float* __restrict__ b2,
                                                 const float* __restrict__ W3,
                                                 float* __restrict__ partial) {
  __shared__ unsigned short As[64 * 64];
  __shared__ unsigned short Bs[256 * 64];
  __shared__ float ps[4][64];
  const int tid  = threadIdx.x;
  const int wv   = tid >> 6;
  const int lane = tid & 63;
  const int bid  = blockIdx.x;
  const int m0 = (bid >> 2) * 64;
  const int nq = bid & 3;                   // n-quarter (256 cols)
  const int n0 = nq * 256;
  const int wn = wv * 64;
  const int r = lane & 15;
  const int g = lane >> 4;
  const int srow = lane >> 3;               // row within 8-row chunk
  const int slot = (lane & 7) ^ srow;       // logical 16B slot this lane fetches

  f32x4 acc[4][4] = {};

  for (int kt = 0; kt < 32; ++kt) {
    const int k0 = kt * 64;
    #pragma unroll
    for (int i = 0; i < 2; ++i) {           // A: 8 chunks of 1KB
      const int c   = i * 4 + wv;
      const int row = c * 8 + srow;
      gload16(A + (size_t)(m0 + row) * H1_N + k0 + slot * 8, (char*)As + c * 1024);
    }
    #pragma unroll
    for (int i = 0; i < 8; ++i) {           // B: 32 chunks of 1KB
      const int c   = i * 4 + wv;
      const int row = c * 8 + srow;
      gload16(Bm + (size_t)(n0 + row) * H1_N + k0 + slot * 8, (char*)Bs + c * 1024);
    }
    __syncthreads();                         // drains vmcnt before compute
    #pragma unroll
    for (int kk = 0; kk < 2; ++kk) {
      bf16x8 af[4], bfr[4];
      #pragma unroll
      for (int mi = 0; mi < 4; ++mi) {
        const int row = mi * 16 + r;
        const int s   = (kk * 4 + g) ^ (row & 7);
        af[mi] = *(const bf16x8*)((const char*)As + row * 128 + s * 16);
      }
      #pragma unroll
      for (int ni = 0; ni < 4; ++ni) {
        const int col = wn + ni * 16 + r;
        const int s   = (kk * 4 + g) ^ (col & 7);
        bfr[ni] = *(const bf16x8*)((const char*)Bs + col * 128 + s * 16);
      }
      #pragma unroll
      for (int mi = 0; mi < 4; ++mi)
        #pragma unroll
        for (int ni = 0; ni < 4; ++ni)
          acc[mi][ni] = __builtin_amdgcn_mfma_f32_16x16x32_bf16(af[mi], bfr[ni], acc[mi][ni], 0, 0, 0);
    }
    __syncthreads();                         // protect LDS before next stage
  }
  // Epilogue: C/D layout col=lane&15 (r), row=g*4+q within fragment.
  // Full-K pre-activations now live in acc: relu+dot with W3 per lane's 4 cols,
  // shfl-reduce the 16-lane col group, then sum the 4 waves' rowsums via LDS.
  float b2v[4], w3v[4];
  #pragma unroll
  for (int ni = 0; ni < 4; ++ni) {
    const int col = n0 + wn + ni * 16 + r;
    b2v[ni] = b2[col];
    w3v[ni] = W3[col];
  }
  float rs[16];
  #pragma unroll
  for (int mi = 0; mi < 4; ++mi)
    #pragma unroll
    for (int q = 0; q < 4; ++q) {
      float s = 0.f;
      #pragma unroll
      for (int ni = 0; ni < 4; ++ni)
        s += fmaxf(acc[mi][ni][q] + b2v[ni], 0.f) * w3v[ni];
      rs[mi*4+q] = s;
    }
  #pragma unroll
  for (int o = 1; o < 16; o <<= 1)
    #pragma unroll
    for (int k = 0; k < 16; ++k)
      rs[k] += __shfl_xor(rs[k], o, 64);
  if (r == 0)
    #pragma unroll
    for (int mi = 0; mi < 4; ++mi)
      #pragma unroll
      for (int q = 0; q < 4; ++q)
        ps[wv][mi*16 + g*4 + q] = rs[mi*4+q];
  __syncthreads();
  if (tid < 64)
    partial[(size_t)nq * (2*B_N) + m0 + tid] =
        ps[0][tid] + ps[1][tid] + ps[2][tid] + ps[3][tid];
}

// K4: out[i] = sum_j partial[j][i] + b3
__global__ __launch_bounds__(256) void k_fin(const float* __restrict__ partial,
                                             const float* __restrict__ b3,
                                             float* __restrict__ out) {
  const int i = blockIdx.x * 256 + threadIdx.x;
  float s = b3[0];
  #pragma unroll
  for (int j = 0; j < 4; ++j) s += partial[(size_t)j * (2*B_N) + i];
  out[i] = s;
}

extern "C" void kernel_launch(void* const* d_in, const int* in_sizes, int n_in,
                              void* d_out, int out_size, void* d_ws, size_t ws_size,
                              hipStream_t stream) {
  const int*   dp   = (const int*)d_in[0];
  const int*   dt   = (const int*)d_in[1];
  const float* conc = (const float*)d_in[2];
  const float* W1   = (const float*)d_in[3];
  const float* b1   = (const float*)d_in[4];
  const float* W2   = (const float*)d_in[5];
  const float* b2   = (const float*)d_in[6];
  const float* W3   = (const float*)d_in[7];
  const float* b3   = (const float*)d_in[8];
  float* out = (float*)d_out;

  // ws layout (bytes) — SAb/SBb are 4000*2048*2 = 16,384,000 B each:
  //   [0,         155656192)  W1b bf16 [38002][2048]  (dead after k_dsum)
  //      aliased after k_dsum by:
  //        h1       bf16 [8192][2048] at 0 .. 33554432
  //        partials f32  [4][8192]    at 33554432 .. 33685504
  //   [155656192, 172040192)  SAb bf16 [4000][2048]
  //   [172040192, 188424192)  SBb bf16 [4000][2048]
  //   [188424192, 192618496)  w2t bf16 [1024][2048]
  //   [192618496, 192622496)  flags u8 [4000]          (total ~192.6 MB)
  char* ws = (char*)d_ws;
  unsigned short* W1b   = (unsigned short*)ws;
  unsigned short* h1    = (unsigned short*)ws;
  float*          parts = (float*)(ws + 33554432);
  unsigned short* SAb   = (unsigned short*)(ws + 155656192);
  unsigned short* SBb   = (unsigned short*)(ws + 172040192);
  unsigned short* w2t   = (unsigned short*)(ws + 188424192);
  unsigned char*  flags = (unsigned char*)(ws + 192618496);

  k_prep<<<40051,  256, 0, stream>>>(W1, W1b, W2, w2t, dp, flags);
  k_dsum<<<D_N,    256, 0, stream>>>(dt, flags, W1b, SAb, SBb);
  k_h1  <<<2*B_N,  256, 0, stream>>>(dp, conc, W1, b1, SAb, SBb, h1);
  k_gemm<<<512,    256, 0, stream>>>(h1, w2t, b2, W3, parts);
  k_fin <<<32,     256, 0, stream>>>(parts, b3, out);
}